// Round 1
// 296.477 us; speedup vs baseline: 1.2130x; 1.2130x over previous
//
#include <hip/hip_runtime.h>
#include <hip/hip_bf16.h>

#define NN 50000
#define EE 800000
#define EP 850000   // EE + NN self-loops
#define DD 128
#define NB 196      // ceil(NN/256)

#define NBUCK 196        // dst buckets: b = d >> 8 (d_max 49999 -> 195)
#define BCAP 8192        // slots per bucket (mean ~4350, 1.9x headroom)
#define E_PER_BLK 4096   // edges per binpass1 block (16/thread)

typedef __attribute__((ext_vector_type(8))) short short8;
typedef __attribute__((ext_vector_type(4))) float f32x4;

__device__ __forceinline__ float bfu(unsigned short u){ return __uint_as_float(((unsigned)u)<<16); }
__device__ __forceinline__ unsigned short f2bs(float x){
  __hip_bfloat16 h = __float2bfloat16(x);
  union { __hip_bfloat16 h; unsigned short u; } cv; cv.h = h; return cv.u;
}

// ---------------- prep: zero bucket cursors (block 0) + pack W tiles (blocks 0..23)
// ---------------- + W@a fragments (blocks 24..119) --------------------------
// Wmf[layer][t=c*4+kb][lane][j] = W[kb*32+(lane>>4)*8+j][c*16+(lane&15)]  (c<8)
// tile 8: n=lane&15: n<8 -> (W@a_src)[k][head n], n>=8 -> (W@a_dst)[k][head n-8]
__global__ void __launch_bounds__(256) prep_kernel(
    const float* __restrict__ W0, const float* __restrict__ as0, const float* __restrict__ ad0,
    const float* __restrict__ W1, const float* __restrict__ as1, const float* __restrict__ ad1,
    const float* __restrict__ W2, const float* __restrict__ as2, const float* __restrict__ ad2,
    unsigned short* __restrict__ Wmf, int* __restrict__ bcur)
{
  const int tid = threadIdx.x;
  if (blockIdx.x == 0 && tid < NBUCK) bcur[tid] = 0;
  if (blockIdx.x < 24){
    // W reformat, tiles 0..31
    const int L = blockIdx.x >> 3, seg = blockIdx.x & 7;
    const float* W = (L == 0) ? W0 : (L == 1) ? W1 : W2;
    int idx = seg*256 + tid;                  // 0..2047
    int t = idx >> 6, lane = idx & 63;        // t 0..31
    int c = t >> 2, kb = t & 3;
    int m = lane & 15, quad = lane >> 4;
    unsigned short out[8];
    #pragma unroll
    for (int j = 0; j < 8; j++){
      int k = kb*32 + quad*8 + j;
      out[j] = f2bs(W[(size_t)k*DD + c*16 + m]);
    }
    *(uint4*)&Wmf[(((size_t)L*36 + t)*64 + lane)*8] = *(const uint4*)out;
  } else if (blockIdx.x < 120){
    // W@a_src / W@a_dst -> tile 8; one wave per (layer,k)
    const int q = blockIdx.x - 24;
    const int wIdx = q*4 + (tid >> 6);        // 0..383
    const int L = wIdx >> 7, k = wIdx & 127;
    const float *W, *as, *ad; int H;
    if (L == 0){ W = W0; as = as0; ad = ad0; H = 8; }
    else if (L == 1){ W = W1; as = as1; ad = ad1; H = 8; }
    else { W = W2; as = as2; ad = ad2; H = 1; }
    const int lane = tid & 63;
    const int c0 = lane*2;
    float w0 = W[(size_t)k*DD + c0];
    float w1 = W[(size_t)k*DD + c0 + 1];
    float ps = w0*as[c0] + w1*as[c0+1];
    float pd = w0*ad[c0] + w1*ad[c0+1];
    if (H == 8){
      #pragma unroll
      for (int off = 1; off <= 4; off <<= 1){   // reduce within 8-lane head groups
        ps += __shfl_xor(ps, off, 64);
        pd += __shfl_xor(pd, off, 64);
      }
    } else {
      #pragma unroll
      for (int off = 1; off <= 32; off <<= 1){  // full-wave reduce
        ps += __shfl_xor(ps, off, 64);
        pd += __shfl_xor(pd, off, 64);
      }
    }
    int srcLane = (lane < 8) ? lane*8 : (lane < 16 ? (lane-8)*8 : 0);
    float vs = __shfl(ps, srcLane, 64);
    float vd = __shfl(pd, srcLane, 64);
    float myv;
    if (H == 8) myv = (lane < 8) ? vs : (lane < 16 ? vd : 0.f);
    else        myv = (lane == 0) ? ps : (lane == 1 ? pd : 0.f);
    const int kb = k >> 5, quad = (k >> 3) & 3, j = k & 7;
    if (lane < 16)
      Wmf[(((size_t)L*36 + 32 + kb)*64 + quad*16 + lane)*8 + j] = f2bs(myv);
  }
}

// ---------------- CSR build: bucketed two-pass counting sort ----------------
// pass 1: bin edges by dst>>8 into per-bucket regions. LDS-aggregated:
// one global atomic per (block,bucket) instead of per edge; packed word
// = (src<<16)|(bucket<<8)|(dst&255). Writes are contiguous runs per bucket.
__global__ void __launch_bounds__(256) binpass1_kernel(const int* __restrict__ ei,
    unsigned int* __restrict__ bins, int* __restrict__ bcur)
{
  __shared__ int h[NBUCK];           // block-local histogram, then LDS cursors
  __shared__ int lofs[NBUCK];        // exclusive scan of h
  __shared__ int gbase[NBUCK];       // reserved global base per bucket
  __shared__ unsigned int st[E_PER_BLK];  // 16 KB staging, grouped by bucket
  __shared__ int buf[256];
  const int tid = threadIdx.x;
  for (int i = tid; i < NBUCK; i += 256) h[i] = 0;
  __syncthreads();

  const int e0 = blockIdx.x * E_PER_BLK;
  unsigned int pk[16];
  #pragma unroll
  for (int k = 0; k < 16; k++){
    int e = e0 + k*256 + tid;
    if (e < EP){
      int s, d;
      if (e < EE){ s = ei[e]; d = ei[EE + e]; } else { s = d = e - EE; }
      int b = d >> 8;
      pk[k] = ((unsigned)s << 16) | ((unsigned)b << 8) | (unsigned)(d & 255);
      atomicAdd(&h[b], 1);
    } else pk[k] = 0xFFFFFFFFu;      // sentinel: s=65535 impossible (s<50000)
  }
  __syncthreads();

  // exclusive scan of h over 256 lanes (pad 0); reserve global space per bucket
  int v = (tid < NBUCK) ? h[tid] : 0;
  buf[tid] = v;
  __syncthreads();
  for (int off = 1; off < 256; off <<= 1){
    int t = (tid >= off) ? buf[tid - off] : 0;
    __syncthreads();
    buf[tid] += t;
    __syncthreads();
  }
  if (tid < NBUCK){
    lofs[tid]  = buf[tid] - v;
    gbase[tid] = (v > 0) ? atomicAdd(&bcur[tid], v) : 0;
    h[tid] = lofs[tid];              // reuse h as LDS placement cursor
  }
  __syncthreads();

  // place into LDS staging grouped by bucket
  #pragma unroll
  for (int k = 0; k < 16; k++){
    if (pk[k] != 0xFFFFFFFFu){
      int b = (pk[k] >> 8) & 255;
      int p = atomicAdd(&h[b], 1);
      st[p] = pk[k];
    }
  }
  __syncthreads();

  // flush: contiguous per-bucket runs -> bins[b*BCAP + gbase[b] + local]
  const int total = buf[255];
  for (int i = tid; i < total; i += 256){
    unsigned int p = st[i];
    int b = (p >> 8) & 255;
    int idx = gbase[b] + (i - lofs[b]);
    if (idx < BCAP) bins[(size_t)b * BCAP + idx] = p;
  }
}

// pass 2: one block per bucket. Redundant scan of bcur gives edge base; LDS
// hist+scan over the 256 local dst -> coalesced rowStart write (replaces the
// global scan kernels); then scatter srcL with LDS cursors into the bucket's
// ~9 KB window (single-XCD, L2-merged -> no write amplification).
__global__ void __launch_bounds__(256) binpass2_kernel(const unsigned int* __restrict__ bins,
    const int* __restrict__ bcur, int* __restrict__ rowStart, unsigned short* __restrict__ srcL)
{
  __shared__ int buf[256];
  __shared__ int lcnt[256];
  __shared__ int lcur[256];
  __shared__ int ebase_s, cnt_s;
  const int b = blockIdx.x;          // 0..195
  const int tid = threadIdx.x;

  int v = (tid < NBUCK) ? bcur[tid] : 0;
  buf[tid] = v;
  lcnt[tid] = 0;
  __syncthreads();
  for (int off = 1; off < 256; off <<= 1){
    int t = (tid >= off) ? buf[tid - off] : 0;
    __syncthreads();
    buf[tid] += t;
    __syncthreads();
  }
  if (tid == b){ ebase_s = buf[tid] - v; cnt_s = v; }
  __syncthreads();
  const int ebase = ebase_s, cnt = cnt_s;
  const unsigned int* mybins = bins + (size_t)b * BCAP;

  // phase A: histogram by local dst
  for (int i = tid; i < cnt; i += 256)
    atomicAdd(&lcnt[mybins[i] & 255], 1);
  __syncthreads();

  // phase B: exclusive scan -> rowStart (coalesced) + init cursors
  int c = lcnt[tid];
  buf[tid] = c;
  __syncthreads();
  for (int off = 1; off < 256; off <<= 1){
    int t = (tid >= off) ? buf[tid - off] : 0;
    __syncthreads();
    buf[tid] += t;
    __syncthreads();
  }
  int excl = buf[tid] - c;
  int d = (b << 8) + tid;
  if (d <= NN) rowStart[d] = ebase + excl;   // d==NN lands in bucket 195 -> EP
  lcur[tid] = ebase + excl;
  __syncthreads();

  // phase C: scatter into this bucket's srcL window
  for (int i = tid; i < cnt; i += 256){
    unsigned int p = mybins[i];
    int pos = atomicAdd(&lcur[p & 255], 1);
    srcL[pos] = (unsigned short)(p >> 16);
  }
}

// ---------------- MFMA GEMM: h = x@W (bf16 out) + al dots via 9th col tile ----------------
// 64 rows/block, 4 waves, 16 rows/wave. A: x rows as bf16 frags; B: pre-packed Wmf in LDS.
template<bool XBF16, int H>
__global__ void __launch_bounds__(256) gemm_mfma_kernel(const void* __restrict__ Xv,
    const unsigned short* __restrict__ Wmf,
    unsigned short* __restrict__ Hout,
    float* __restrict__ alS, float* __restrict__ alD)
{
  __shared__ unsigned short wl[36*64*8];    // 36 KB = 2304 uint4
  const int tid = threadIdx.x;
  {
    const uint4* src = (const uint4*)Wmf;
    uint4* dst = (uint4*)wl;
    #pragma unroll
    for (int i = 0; i < 9; i++)             // 9*256 = 2304 uint4 — full copy
      dst[tid + i*256] = src[tid + i*256];
  }
  const int lane = tid & 63, wv = tid >> 6;
  const int r0 = blockIdx.x*64 + wv*16;
  const int m = lane & 15, quad = lane >> 4;
  const int row = r0 + m;
  const bool rowOK = row < NN;

  short8 a[4];
  if (XBF16){
    const short* Xb = (const short*)Xv;
    #pragma unroll
    for (int kb = 0; kb < 4; kb++){
      if (rowOK) a[kb] = *(const short8*)&Xb[(size_t)row*DD + kb*32 + quad*8];
      else       a[kb] = (short8){0,0,0,0,0,0,0,0};
    }
  } else {
    const float* Xf = (const float*)Xv;
    #pragma unroll
    for (int kb = 0; kb < 4; kb++){
      if (rowOK){
        float4 f0 = *(const float4*)&Xf[(size_t)row*DD + kb*32 + quad*8];
        float4 f1 = *(const float4*)&Xf[(size_t)row*DD + kb*32 + quad*8 + 4];
        union { short8 v; unsigned short u[8]; } cv;
        cv.u[0]=f2bs(f0.x); cv.u[1]=f2bs(f0.y); cv.u[2]=f2bs(f0.z); cv.u[3]=f2bs(f0.w);
        cv.u[4]=f2bs(f1.x); cv.u[5]=f2bs(f1.y); cv.u[6]=f2bs(f1.z); cv.u[7]=f2bs(f1.w);
        a[kb] = cv.v;
      } else a[kb] = (short8){0,0,0,0,0,0,0,0};
    }
  }
  __syncthreads();

  f32x4 acc[9];
  #pragma unroll
  for (int c = 0; c < 9; c++) acc[c] = (f32x4){0.f,0.f,0.f,0.f};
  #pragma unroll
  for (int c = 0; c < 9; c++){
    #pragma unroll
    for (int kb = 0; kb < 4; kb++){
      short8 b = *(const short8*)&wl[((c*4 + kb)*64 + lane)*8];
      acc[c] = __builtin_amdgcn_mfma_f32_16x16x32_bf16(a[kb], b, acc[c], 0, 0, 0);
    }
  }

  // h store: D layout col=lane&15, row=quad*4+reg  [m89/m91-verified]
  #pragma unroll
  for (int c = 0; c < 8; c++){
    #pragma unroll
    for (int r = 0; r < 4; r++){
      int rw = r0 + quad*4 + r;
      if (rw < NN) Hout[(size_t)rw*DD + c*16 + m] = f2bs(acc[c][r]);
    }
  }
  // al store from tile 8
  #pragma unroll
  for (int r = 0; r < 4; r++){
    int rw = r0 + quad*4 + r;
    if (rw < NN){
      float v = acc[8][r];
      if (H == 8){
        if (m < 8) alS[rw*8 + m]       = v;
        else       alD[rw*8 + (m - 8)] = v;
      } else {
        if (m == 0)      alS[rw] = v;
        else if (m == 1) alD[rw] = v;
      }
    }
  }
}

// ---------------- fused: per-dst softmax + gather-aggregate + bias + LN (+ELU) ----------------
// one wave per dst node; lane covers channels 2*lane, 2*lane+1.
// Round-6 proven structure: s uniform across wave per step -> alS row load is a
// BROADCAST (one 32B transaction), hB row load fully coalesced. 4x unroll for MLP.
template<int H, bool FINAL>
__global__ void __launch_bounds__(256) aggln_kernel(
    const int* __restrict__ rowStart, const unsigned short* __restrict__ srcL,
    const float* __restrict__ alS, const float* __restrict__ alD,
    const unsigned short* __restrict__ hB,
    const float* __restrict__ b, const float* __restrict__ g, const float* __restrict__ be,
    void* __restrict__ outv)
{
  const int lane = threadIdx.x & 63;
  const int d    = blockIdx.x*4 + (threadIdx.x >> 6);
  const int C    = DD / H;
  const int c0   = lane*2;
  const int hd   = c0 / C;
  const int start = rowStart[d], end = rowStart[d+1];
  const float aldv = alD[d*H + hd];

  float ssum = 0.f, a0 = 0.f, a1 = 0.f;
  for (int base = start; base < end; base += 64){
    const int cnt = min(64, end - base);
    int myS = (base + lane < end) ? (int)srcL[base + lane] : 0;
    int j = 0;
    for (; j + 4 <= cnt; j += 4){
      int s0 = __shfl(myS, j,   64);
      int s1 = __shfl(myS, j+1, 64);
      int s2 = __shfl(myS, j+2, 64);
      int s3 = __shfl(myS, j+3, 64);
      ushort2 h0 = *(const ushort2*)&hB[(size_t)s0*DD + c0];
      ushort2 h1 = *(const ushort2*)&hB[(size_t)s1*DD + c0];
      ushort2 h2 = *(const ushort2*)&hB[(size_t)s2*DD + c0];
      ushort2 h3 = *(const ushort2*)&hB[(size_t)s3*DD + c0];
      float e0 = alS[s0*H + hd] + aldv;
      float e1 = alS[s1*H + hd] + aldv;
      float e2 = alS[s2*H + hd] + aldv;
      float e3 = alS[s3*H + hd] + aldv;
      e0 = e0 > 0.f ? e0 : 0.2f*e0;
      e1 = e1 > 0.f ? e1 : 0.2f*e1;
      e2 = e2 > 0.f ? e2 : 0.2f*e2;
      e3 = e3 > 0.f ? e3 : 0.2f*e3;
      float w0 = __expf(fminf(e0, 80.f));
      float w1 = __expf(fminf(e1, 80.f));
      float w2 = __expf(fminf(e2, 80.f));
      float w3 = __expf(fminf(e3, 80.f));
      ssum += (w0 + w1) + (w2 + w3);
      a0 = fmaf(bfu(h0.x), w0, a0);  a1 = fmaf(bfu(h0.y), w0, a1);
      a0 = fmaf(bfu(h1.x), w1, a0);  a1 = fmaf(bfu(h1.y), w1, a1);
      a0 = fmaf(bfu(h2.x), w2, a0);  a1 = fmaf(bfu(h2.y), w2, a1);
      a0 = fmaf(bfu(h3.x), w3, a0);  a1 = fmaf(bfu(h3.y), w3, a1);
    }
    for (; j < cnt; j++){
      int s0 = __shfl(myS, j, 64);
      ushort2 h0 = *(const ushort2*)&hB[(size_t)s0*DD + c0];
      float e0 = alS[s0*H + hd] + aldv;
      e0 = e0 > 0.f ? e0 : 0.2f*e0;
      float w0 = __expf(fminf(e0, 80.f));
      ssum += w0;
      a0 = fmaf(bfu(h0.x), w0, a0);
      a1 = fmaf(bfu(h0.y), w0, a1);
    }
  }
  const float sinv = 1.f / ssum;

  // bias + LayerNorm across the wave's 128 channels
  float v0 = a0*sinv + b[c0], v1 = a1*sinv + b[c0+1];
  float s2 = v0 + v1;
  #pragma unroll
  for (int off = 32; off >= 1; off >>= 1) s2 += __shfl_xor(s2, off, 64);
  float mu = s2 * (1.0f/128.0f);
  float d0 = v0 - mu, d1 = v1 - mu;
  float q = d0*d0 + d1*d1;
  #pragma unroll
  for (int off = 32; off >= 1; off >>= 1) q += __shfl_xor(q, off, 64);
  float r = rsqrtf(q*(1.0f/128.0f) + 1e-5f);
  float y0 = d0*r*g[c0]   + be[c0];
  float y1 = d1*r*g[c0+1] + be[c0+1];
  if (FINAL){
    *(float2*)&((float*)outv)[(size_t)d*DD + c0] = make_float2(y0, y1);
  } else {
    y0 = y0 > 0.f ? y0 : __expf(y0) - 1.f;   // ELU
    y1 = y1 > 0.f ? y1 : __expf(y1) - 1.f;
    ushort2 o; o.x = f2bs(y0); o.y = f2bs(y1);
    *(ushort2*)&((unsigned short*)outv)[(size_t)d*DD + c0] = o;
  }
}

// ---------------- host-side layer driver ----------------
template<bool XBF16, int H, bool FINAL>
static void run_layer(const void* x, const unsigned short* WmfL,
                      const float* b, const float* g, const float* be,
                      const int* rowStart, const unsigned short* srcL,
                      unsigned short* hB, float* alS, float* alD,
                      void* outv, hipStream_t stream)
{
  gemm_mfma_kernel<XBF16, H><<<782, 256, 0, stream>>>(x, WmfL, hB, alS, alD);
  aggln_kernel<H, FINAL><<<12500, 256, 0, stream>>>(rowStart, srcL, alS, alD, hB,
                                                    b, g, be, outv);
}

extern "C" void kernel_launch(void* const* d_in, const int* in_sizes, int n_in,
                              void* d_out, int out_size, void* d_ws, size_t ws_size,
                              hipStream_t stream)
{
  // ws layout (~31 MB)
  char* w = (char*)d_ws;
  unsigned short* accB = (unsigned short*)w;     w += (size_t)NN*DD*2;   // 12.8 MB (bf16 x-next)
  unsigned short* hB   = (unsigned short*)w;     w += (size_t)NN*DD*2;   // 12.8 MB (bf16 h)
  float* alS      = (float*)w;                   w += (size_t)NN*8*4;    // 1.6 MB
  float* alD      = (float*)w;                   w += (size_t)NN*8*4;    // 1.6 MB
  unsigned short* Wmf = (unsigned short*)w;      w += (size_t)3*36*64*8*2; // 216 KB
  int*   rowStart = (int*)w;                     w += (size_t)(NN+1)*4;  // 200 KB
  int*   bcur     = (int*)w;                     w += 1024;              // bucket counts/cursors
  unsigned short* srcL = (unsigned short*)w;     w += (size_t)EP*2;      // 1.7 MB
  if (ws_size < (size_t)(w - (char*)d_ws)) return;

  // bins (196*8192*4 = 6.4 MB) aliases accB: consumed before layer 0 writes accB
  unsigned int* bins = (unsigned int*)accB;

  const float* x  = (const float*)d_in[0];
  const int*   ei = (const int*)d_in[1];
  const float *W0=(const float*)d_in[2], *as0=(const float*)d_in[3], *ad0=(const float*)d_in[4];
  const float *b0=(const float*)d_in[5], *g0=(const float*)d_in[6], *be0=(const float*)d_in[7];
  const float *W1=(const float*)d_in[8], *as1=(const float*)d_in[9], *ad1=(const float*)d_in[10];
  const float *b1=(const float*)d_in[11],*g1=(const float*)d_in[12],*be1=(const float*)d_in[13];
  const float *W2=(const float*)d_in[14],*as2=(const float*)d_in[15],*ad2=(const float*)d_in[16];
  const float *b2=(const float*)d_in[17],*g2=(const float*)d_in[18],*be2=(const float*)d_in[19];

  prep_kernel<<<NB, 256, 0, stream>>>(W0, as0, ad0, W1, as1, ad1, W2, as2, ad2, Wmf, bcur);
  binpass1_kernel<<<(EP + E_PER_BLK - 1)/E_PER_BLK, 256, 0, stream>>>(ei, bins, bcur);
  binpass2_kernel<<<NBUCK, 256, 0, stream>>>(bins, bcur, rowStart, srcL);

  // layer 0: x = f32 input, 8 heads, ELU -> accB (bf16)
  run_layer<false, 8, false>(x,    Wmf,            b0, g0, be0,
                             rowStart, srcL, hB, alS, alD, accB, stream);
  // layer 1: x = accB (bf16), 8 heads, ELU -> accB
  run_layer<true, 8, false>(accB, Wmf + (size_t)36*64*8,   b1, g1, be1,
                             rowStart, srcL, hB, alS, alD, accB, stream);
  // layer 2: x = accB (bf16), 1 head, LN only -> d_out (f32)
  run_layer<true, 1, true>(accB, Wmf + (size_t)2*36*64*8,  b2, g2, be2,
                             rowStart, srcL, hB, alS, alD, d_out, stream);
}

// Round 2
// 283.982 us; speedup vs baseline: 1.2664x; 1.0440x over previous
//
#include <hip/hip_runtime.h>
#include <hip/hip_bf16.h>

#define NN 50000
#define EE 800000
#define EP 850000   // EE + NN self-loops
#define DD 128
#define NB 196      // ceil(NN/256)

#define NBUCK 196        // dst buckets: b = d >> 8 (d_max 49999 -> 195)
#define BCAP 8192        // slots per bucket (mean ~4350, 1.9x headroom)
#define E_PER_BLK 4096   // edges per binpass1 block (16/thread)

typedef __attribute__((ext_vector_type(8))) short short8;
typedef __attribute__((ext_vector_type(4))) float f32x4;

__device__ __forceinline__ float bfu(unsigned short u){ return __uint_as_float(((unsigned)u)<<16); }
__device__ __forceinline__ unsigned short f2bs(float x){
  __hip_bfloat16 h = __float2bfloat16(x);
  union { __hip_bfloat16 h; unsigned short u; } cv; cv.h = h; return cv.u;
}

// ---------------- prep: zero bucket cursors (block 0) + pack W tiles (blocks 0..23)
// ---------------- + W@a fragments (blocks 24..119) --------------------------
__global__ void __launch_bounds__(256) prep_kernel(
    const float* __restrict__ W0, const float* __restrict__ as0, const float* __restrict__ ad0,
    const float* __restrict__ W1, const float* __restrict__ as1, const float* __restrict__ ad1,
    const float* __restrict__ W2, const float* __restrict__ as2, const float* __restrict__ ad2,
    unsigned short* __restrict__ Wmf, int* __restrict__ bcur)
{
  const int tid = threadIdx.x;
  if (blockIdx.x == 0 && tid < NBUCK) bcur[tid] = 0;
  if (blockIdx.x < 24){
    // W reformat, tiles 0..31
    const int L = blockIdx.x >> 3, seg = blockIdx.x & 7;
    const float* W = (L == 0) ? W0 : (L == 1) ? W1 : W2;
    int idx = seg*256 + tid;                  // 0..2047
    int t = idx >> 6, lane = idx & 63;        // t 0..31
    int c = t >> 2, kb = t & 3;
    int m = lane & 15, quad = lane >> 4;
    unsigned short out[8];
    #pragma unroll
    for (int j = 0; j < 8; j++){
      int k = kb*32 + quad*8 + j;
      out[j] = f2bs(W[(size_t)k*DD + c*16 + m]);
    }
    *(uint4*)&Wmf[(((size_t)L*36 + t)*64 + lane)*8] = *(const uint4*)out;
  } else if (blockIdx.x < 120){
    // W@a_src / W@a_dst -> tile 8; one wave per (layer,k)
    const int q = blockIdx.x - 24;
    const int wIdx = q*4 + (tid >> 6);        // 0..383
    const int L = wIdx >> 7, k = wIdx & 127;
    const float *W, *as, *ad; int H;
    if (L == 0){ W = W0; as = as0; ad = ad0; H = 8; }
    else if (L == 1){ W = W1; as = as1; ad = ad1; H = 8; }
    else { W = W2; as = as2; ad = ad2; H = 1; }
    const int lane = tid & 63;
    const int c0 = lane*2;
    float w0 = W[(size_t)k*DD + c0];
    float w1 = W[(size_t)k*DD + c0 + 1];
    float ps = w0*as[c0] + w1*as[c0+1];
    float pd = w0*ad[c0] + w1*ad[c0+1];
    if (H == 8){
      #pragma unroll
      for (int off = 1; off <= 4; off <<= 1){   // reduce within 8-lane head groups
        ps += __shfl_xor(ps, off, 64);
        pd += __shfl_xor(pd, off, 64);
      }
    } else {
      #pragma unroll
      for (int off = 1; off <= 32; off <<= 1){  // full-wave reduce
        ps += __shfl_xor(ps, off, 64);
        pd += __shfl_xor(pd, off, 64);
      }
    }
    int srcLane = (lane < 8) ? lane*8 : (lane < 16 ? (lane-8)*8 : 0);
    float vs = __shfl(ps, srcLane, 64);
    float vd = __shfl(pd, srcLane, 64);
    float myv;
    if (H == 8) myv = (lane < 8) ? vs : (lane < 16 ? vd : 0.f);
    else        myv = (lane == 0) ? ps : (lane == 1 ? pd : 0.f);
    const int kb = k >> 5, quad = (k >> 3) & 3, j = k & 7;
    if (lane < 16)
      Wmf[(((size_t)L*36 + 32 + kb)*64 + quad*16 + lane)*8 + j] = f2bs(myv);
  }
}

// ---------------- CSR build: bucketed two-pass counting sort ----------------
__global__ void __launch_bounds__(256) binpass1_kernel(const int* __restrict__ ei,
    unsigned int* __restrict__ bins, int* __restrict__ bcur)
{
  __shared__ int h[NBUCK];           // block-local histogram, then LDS cursors
  __shared__ int lofs[NBUCK];        // exclusive scan of h
  __shared__ int gbase[NBUCK];       // reserved global base per bucket
  __shared__ unsigned int st[E_PER_BLK];  // 16 KB staging, grouped by bucket
  __shared__ int buf[256];
  const int tid = threadIdx.x;
  for (int i = tid; i < NBUCK; i += 256) h[i] = 0;
  __syncthreads();

  const int e0 = blockIdx.x * E_PER_BLK;
  unsigned int pk[16];
  #pragma unroll
  for (int k = 0; k < 16; k++){
    int e = e0 + k*256 + tid;
    if (e < EP){
      int s, d;
      if (e < EE){ s = ei[e]; d = ei[EE + e]; } else { s = d = e - EE; }
      int b = d >> 8;
      pk[k] = ((unsigned)s << 16) | ((unsigned)b << 8) | (unsigned)(d & 255);
      atomicAdd(&h[b], 1);
    } else pk[k] = 0xFFFFFFFFu;      // sentinel: s=65535 impossible (s<50000)
  }
  __syncthreads();

  // exclusive scan of h over 256 lanes (pad 0); reserve global space per bucket
  int v = (tid < NBUCK) ? h[tid] : 0;
  buf[tid] = v;
  __syncthreads();
  for (int off = 1; off < 256; off <<= 1){
    int t = (tid >= off) ? buf[tid - off] : 0;
    __syncthreads();
    buf[tid] += t;
    __syncthreads();
  }
  if (tid < NBUCK){
    lofs[tid]  = buf[tid] - v;
    gbase[tid] = (v > 0) ? atomicAdd(&bcur[tid], v) : 0;
    h[tid] = lofs[tid];              // reuse h as LDS placement cursor
  }
  __syncthreads();

  // place into LDS staging grouped by bucket
  #pragma unroll
  for (int k = 0; k < 16; k++){
    if (pk[k] != 0xFFFFFFFFu){
      int b = (pk[k] >> 8) & 255;
      int p = atomicAdd(&h[b], 1);
      st[p] = pk[k];
    }
  }
  __syncthreads();

  // flush: contiguous per-bucket runs -> bins[b*BCAP + gbase[b] + local]
  const int total = buf[255];
  for (int i = tid; i < total; i += 256){
    unsigned int p = st[i];
    int b = (p >> 8) & 255;
    int idx = gbase[b] + (i - lofs[b]);
    if (idx < BCAP) bins[(size_t)b * BCAP + idx] = p;
  }
}

// pass 2: one block per bucket; LDS hist+scan -> coalesced rowStart; LDS-cursor scatter.
__global__ void __launch_bounds__(256) binpass2_kernel(const unsigned int* __restrict__ bins,
    const int* __restrict__ bcur, int* __restrict__ rowStart, unsigned short* __restrict__ srcL)
{
  __shared__ int buf[256];
  __shared__ int lcnt[256];
  __shared__ int lcur[256];
  __shared__ int ebase_s, cnt_s;
  const int b = blockIdx.x;          // 0..195
  const int tid = threadIdx.x;

  int v = (tid < NBUCK) ? bcur[tid] : 0;
  buf[tid] = v;
  lcnt[tid] = 0;
  __syncthreads();
  for (int off = 1; off < 256; off <<= 1){
    int t = (tid >= off) ? buf[tid - off] : 0;
    __syncthreads();
    buf[tid] += t;
    __syncthreads();
  }
  if (tid == b){ ebase_s = buf[tid] - v; cnt_s = v; }
  __syncthreads();
  const int ebase = ebase_s, cnt = cnt_s;
  const unsigned int* mybins = bins + (size_t)b * BCAP;

  // phase A: histogram by local dst
  for (int i = tid; i < cnt; i += 256)
    atomicAdd(&lcnt[mybins[i] & 255], 1);
  __syncthreads();

  // phase B: exclusive scan -> rowStart (coalesced) + init cursors
  int c = lcnt[tid];
  buf[tid] = c;
  __syncthreads();
  for (int off = 1; off < 256; off <<= 1){
    int t = (tid >= off) ? buf[tid - off] : 0;
    __syncthreads();
    buf[tid] += t;
    __syncthreads();
  }
  int excl = buf[tid] - c;
  int d = (b << 8) + tid;
  if (d <= NN) rowStart[d] = ebase + excl;   // d==NN lands in bucket 195 -> EP
  lcur[tid] = ebase + excl;
  __syncthreads();

  // phase C: scatter into this bucket's srcL window
  for (int i = tid; i < cnt; i += 256){
    unsigned int p = mybins[i];
    int pos = atomicAdd(&lcur[p & 255], 1);
    srcL[pos] = (unsigned short)(p >> 16);
  }
}

// ---------------- MFMA GEMM: h = x@W (bf16 out) + al dots via 9th col tile ----------------
template<bool XBF16, int H>
__global__ void __launch_bounds__(256) gemm_mfma_kernel(const void* __restrict__ Xv,
    const unsigned short* __restrict__ Wmf,
    unsigned short* __restrict__ Hout,
    float* __restrict__ alS, float* __restrict__ alD)
{
  __shared__ unsigned short wl[36*64*8];    // 36 KB = 2304 uint4
  const int tid = threadIdx.x;
  {
    const uint4* src = (const uint4*)Wmf;
    uint4* dst = (uint4*)wl;
    #pragma unroll
    for (int i = 0; i < 9; i++)             // 9*256 = 2304 uint4 — full copy
      dst[tid + i*256] = src[tid + i*256];
  }
  const int lane = tid & 63, wv = tid >> 6;
  const int r0 = blockIdx.x*64 + wv*16;
  const int m = lane & 15, quad = lane >> 4;
  const int row = r0 + m;
  const bool rowOK = row < NN;

  short8 a[4];
  if (XBF16){
    const short* Xb = (const short*)Xv;
    #pragma unroll
    for (int kb = 0; kb < 4; kb++){
      if (rowOK) a[kb] = *(const short8*)&Xb[(size_t)row*DD + kb*32 + quad*8];
      else       a[kb] = (short8){0,0,0,0,0,0,0,0};
    }
  } else {
    const float* Xf = (const float*)Xv;
    #pragma unroll
    for (int kb = 0; kb < 4; kb++){
      if (rowOK){
        float4 f0 = *(const float4*)&Xf[(size_t)row*DD + kb*32 + quad*8];
        float4 f1 = *(const float4*)&Xf[(size_t)row*DD + kb*32 + quad*8 + 4];
        union { short8 v; unsigned short u[8]; } cv;
        cv.u[0]=f2bs(f0.x); cv.u[1]=f2bs(f0.y); cv.u[2]=f2bs(f0.z); cv.u[3]=f2bs(f0.w);
        cv.u[4]=f2bs(f1.x); cv.u[5]=f2bs(f1.y); cv.u[6]=f2bs(f1.z); cv.u[7]=f2bs(f1.w);
        a[kb] = cv.v;
      } else a[kb] = (short8){0,0,0,0,0,0,0,0};
    }
  }
  __syncthreads();

  f32x4 acc[9];
  #pragma unroll
  for (int c = 0; c < 9; c++) acc[c] = (f32x4){0.f,0.f,0.f,0.f};
  #pragma unroll
  for (int c = 0; c < 9; c++){
    #pragma unroll
    for (int kb = 0; kb < 4; kb++){
      short8 b = *(const short8*)&wl[((c*4 + kb)*64 + lane)*8];
      acc[c] = __builtin_amdgcn_mfma_f32_16x16x32_bf16(a[kb], b, acc[c], 0, 0, 0);
    }
  }

  // h store: D layout col=lane&15, row=quad*4+reg  [m89/m91-verified]
  #pragma unroll
  for (int c = 0; c < 8; c++){
    #pragma unroll
    for (int r = 0; r < 4; r++){
      int rw = r0 + quad*4 + r;
      if (rw < NN) Hout[(size_t)rw*DD + c*16 + m] = f2bs(acc[c][r]);
    }
  }
  // al store from tile 8
  #pragma unroll
  for (int r = 0; r < 4; r++){
    int rw = r0 + quad*4 + r;
    if (rw < NN){
      float v = acc[8][r];
      if (H == 8){
        if (m < 8) alS[rw*8 + m]       = v;
        else       alD[rw*8 + (m - 8)] = v;
      } else {
        if (m == 0)      alS[rw] = v;
        else if (m == 1) alD[rw] = v;
      }
    }
  }
}

// ---------------- fused: per-dst softmax + gather-aggregate + bias + LN (+ELU) ----------------
// one wave per dst node; lane covers channels 2*lane, 2*lane+1.
// R1 rewrite: edge metadata goes SCALAR. start/end hoisted to SGPR via
// readfirstlane; srcL read as uniform dwords (s_load path, 2 edges/word,
// SALU extraction); hB/alS row bases are SGPR pointers (SALU adds) so the
// vector loads use saddr + constant lane offset -> ~9 VALU/edge
// (2 leaky + 2 exp + 1 sum + 2 unpack + 2 fma). No shfl, no clamp.
template<int H, bool FINAL>
__global__ void __launch_bounds__(256) aggln_kernel(
    const int* __restrict__ rowStart, const unsigned short* __restrict__ srcL,
    const float* __restrict__ alS, const float* __restrict__ alD,
    const unsigned short* __restrict__ hB,
    const float* __restrict__ b, const float* __restrict__ g, const float* __restrict__ be,
    void* __restrict__ outv)
{
  const int lane = threadIdx.x & 63;
  const int d    = blockIdx.x*4 + (threadIdx.x >> 6);
  const int C    = DD / H;
  const int c0   = lane*2;
  const int hd   = c0 / C;
  const int start = __builtin_amdgcn_readfirstlane(rowStart[d]);
  const int end   = __builtin_amdgcn_readfirstlane(rowStart[d+1]);
  const float aldv = alD[d*H + hd];

  float ssum = 0.f, a0 = 0.f, a1 = 0.f;
  const unsigned int* __restrict__ sw = (const unsigned int*)srcL;

  // per-edge body: s is wave-uniform (SGPR) -> row bases are SALU
  #define PROC(sv) { \
    int s_ = (sv); \
    const unsigned short* hr_ = hB + (size_t)s_*DD; \
    const float* ar_ = alS + s_*H; \
    unsigned int hw_ = *(const unsigned int*)&hr_[c0]; \
    float e_ = ar_[hd] + aldv; \
    e_ = fmaxf(e_, 0.2f*e_); \
    float w_ = __expf(e_); \
    ssum += w_; \
    a0 = fmaf(__uint_as_float(hw_ << 16),          w_, a0); \
    a1 = fmaf(__uint_as_float(hw_ & 0xFFFF0000u),  w_, a1); \
  }

  int jw = start >> 1;
  if (start & 1){                         // head: odd start -> hi half only
    unsigned int w = sw[jw]; PROC((int)(w >> 16)); jw++;
  }
  const int jwF = end >> 1;               // words with both edges valid
  for (; jw + 2 <= jwF; jw += 2){         // 4 edges per iteration
    unsigned int w0 = sw[jw], w1 = sw[jw+1];
    PROC((int)(w0 & 0xFFFFu)); PROC((int)(w0 >> 16));
    PROC((int)(w1 & 0xFFFFu)); PROC((int)(w1 >> 16));
  }
  for (; jw < jwF; ++jw){
    unsigned int w = sw[jw];
    PROC((int)(w & 0xFFFFu)); PROC((int)(w >> 16));
  }
  if (end & 1){                           // tail: odd end -> lo half only
    unsigned int w = sw[jwF]; PROC((int)(w & 0xFFFFu));
  }
  #undef PROC

  const float sinv = 1.f / ssum;

  // bias + LayerNorm across the wave's 128 channels
  float v0 = a0*sinv + b[c0], v1 = a1*sinv + b[c0+1];
  float s2 = v0 + v1;
  #pragma unroll
  for (int off = 32; off >= 1; off >>= 1) s2 += __shfl_xor(s2, off, 64);
  float mu = s2 * (1.0f/128.0f);
  float d0 = v0 - mu, d1 = v1 - mu;
  float q = d0*d0 + d1*d1;
  #pragma unroll
  for (int off = 32; off >= 1; off >>= 1) q += __shfl_xor(q, off, 64);
  float r = rsqrtf(q*(1.0f/128.0f) + 1e-5f);
  float y0 = d0*r*g[c0]   + be[c0];
  float y1 = d1*r*g[c0+1] + be[c0+1];
  if (FINAL){
    *(float2*)&((float*)outv)[(size_t)d*DD + c0] = make_float2(y0, y1);
  } else {
    y0 = y0 > 0.f ? y0 : __expf(y0) - 1.f;   // ELU
    y1 = y1 > 0.f ? y1 : __expf(y1) - 1.f;
    ushort2 o; o.x = f2bs(y0); o.y = f2bs(y1);
    *(ushort2*)&((unsigned short*)outv)[(size_t)d*DD + c0] = o;
  }
}

// ---------------- host-side layer driver ----------------
template<bool XBF16, int H, bool FINAL>
static void run_layer(const void* x, const unsigned short* WmfL,
                      const float* b, const float* g, const float* be,
                      const int* rowStart, const unsigned short* srcL,
                      unsigned short* hB, float* alS, float* alD,
                      void* outv, hipStream_t stream)
{
  gemm_mfma_kernel<XBF16, H><<<782, 256, 0, stream>>>(x, WmfL, hB, alS, alD);
  aggln_kernel<H, FINAL><<<12500, 256, 0, stream>>>(rowStart, srcL, alS, alD, hB,
                                                    b, g, be, outv);
}

extern "C" void kernel_launch(void* const* d_in, const int* in_sizes, int n_in,
                              void* d_out, int out_size, void* d_ws, size_t ws_size,
                              hipStream_t stream)
{
  // ws layout (~31 MB)
  char* w = (char*)d_ws;
  unsigned short* accB = (unsigned short*)w;     w += (size_t)NN*DD*2;   // 12.8 MB (bf16 x-next)
  unsigned short* hB   = (unsigned short*)w;     w += (size_t)NN*DD*2;   // 12.8 MB (bf16 h)
  float* alS      = (float*)w;                   w += (size_t)NN*8*4;    // 1.6 MB
  float* alD      = (float*)w;                   w += (size_t)NN*8*4;    // 1.6 MB
  unsigned short* Wmf = (unsigned short*)w;      w += (size_t)3*36*64*8*2; // 216 KB
  int*   rowStart = (int*)w;                     w += (size_t)(NN+1)*4;  // 200 KB
  int*   bcur     = (int*)w;                     w += 1024;              // bucket counts/cursors
  unsigned short* srcL = (unsigned short*)w;     w += (size_t)EP*2;      // 1.7 MB
  if (ws_size < (size_t)(w - (char*)d_ws)) return;

  // bins (196*8192*4 = 6.4 MB) aliases accB: consumed before layer 0 writes accB
  unsigned int* bins = (unsigned int*)accB;

  const float* x  = (const float*)d_in[0];
  const int*   ei = (const int*)d_in[1];
  const float *W0=(const float*)d_in[2], *as0=(const float*)d_in[3], *ad0=(const float*)d_in[4];
  const float *b0=(const float*)d_in[5], *g0=(const float*)d_in[6], *be0=(const float*)d_in[7];
  const float *W1=(const float*)d_in[8], *as1=(const float*)d_in[9], *ad1=(const float*)d_in[10];
  const float *b1=(const float*)d_in[11],*g1=(const float*)d_in[12],*be1=(const float*)d_in[13];
  const float *W2=(const float*)d_in[14],*as2=(const float*)d_in[15],*ad2=(const float*)d_in[16];
  const float *b2=(const float*)d_in[17],*g2=(const float*)d_in[18],*be2=(const float*)d_in[19];

  prep_kernel<<<NB, 256, 0, stream>>>(W0, as0, ad0, W1, as1, ad1, W2, as2, ad2, Wmf, bcur);
  binpass1_kernel<<<(EP + E_PER_BLK - 1)/E_PER_BLK, 256, 0, stream>>>(ei, bins, bcur);
  binpass2_kernel<<<NBUCK, 256, 0, stream>>>(bins, bcur, rowStart, srcL);

  // layer 0: x = f32 input, 8 heads, ELU -> accB (bf16)
  run_layer<false, 8, false>(x,    Wmf,            b0, g0, be0,
                             rowStart, srcL, hB, alS, alD, accB, stream);
  // layer 1: x = accB (bf16), 8 heads, ELU -> accB
  run_layer<true, 8, false>(accB, Wmf + (size_t)36*64*8,   b1, g1, be1,
                             rowStart, srcL, hB, alS, alD, accB, stream);
  // layer 2: x = accB (bf16), 1 head, LN only -> d_out (f32)
  run_layer<true, 1, true>(accB, Wmf + (size_t)2*36*64*8,  b2, g2, be2,
                             rowStart, srcL, hB, alS, alD, d_out, stream);
}